// Round 11
// baseline (289.345 us; speedup 1.0000x reference)
//
#include <hip/hip_runtime.h>
#include <hip/hip_bf16.h>

// Problem constants (B=8192, D=128 from reference setup_inputs)
constexpr int Bh = 8192;
constexpr int Nn = 16384;   // 2*B
constexpr int Dd = 128;
constexpr float EPS = 1e-8f;
constexpr float LN2 = 0.69314718056f;
constexpr float SCL = 1.69864363f;   // sqrt(2*log2e): dot(SCL*a,SCL*b) = sim/tau*log2e

// Geometry (R10, best measured): 128-row x 64-col half-tiles, 16 KB staged B,
// 32 KB LDS dbuf -> 4-5 blocks/CU. cum2(t) = t*(257-t); total 128*129 = 16512.
constexpr int K_TILES = 16;         // half-tiles per block
constexpr int N_TILES = 16512;
constexpr int N_BLOCKS = N_TILES / K_TILES;   // 1032, exact

typedef short bf16x8 __attribute__((ext_vector_type(8)));
typedef float f32x4 __attribute__((ext_vector_type(4)));

// half-tile index g -> row tile t: largest t with cum2(t) = t*(257-t) <= g
__device__ __forceinline__ int row_tile_of(int g) {
    int t = (int)((257.0f - sqrtf((float)(66049 - 4 * g))) * 0.5f);
    t = t < 0 ? 0 : (t > 127 ? 127 : t);
    while (t * (257 - t) > g) --t;
    while ((t + 1) * (256 - t) <= g) ++t;
    return t;
}

// row-credit flush: reduce rs over the 16 col-lanes, one atomic per row
__device__ __forceinline__ void flush_rs(float* __restrict__ rowsum, int rowW,
                                         float (&rs)[2][4], int q, int c) {
#pragma unroll
    for (int s = 0; s < 2; ++s)
#pragma unroll
        for (int r = 0; r < 4; ++r) {
            float v = rs[s][r];
            v += __shfl_xor(v, 1);
            v += __shfl_xor(v, 2);
            v += __shfl_xor(v, 4);
            v += __shfl_xor(v, 8);
            if (c == 0) atomicAdd(&rowsum[rowW + s * 16 + q * 4 + r], v);
            rs[s][r] = 0.f;
        }
}

// col-credit flush (deferred one half-tile): reduce over q, one atomic per col
__device__ __forceinline__ void colflush(float* __restrict__ rowsum,
                                         float (&csumP)[4], int C0P, int lane, int c) {
#pragma unroll
    for (int st = 0; st < 4; ++st) {
        float v = csumP[st];
        v += __shfl_xor(v, 16);
        v += __shfl_xor(v, 32);
        if (lane < 16) atomicAdd(&rowsum[C0P + st * 16 + c], v);
    }
}

// ---- R11 fused staging: convert folded into the stage (bf16 z buffer GONE).
// stage_load: issue 8 float4 loads of fp32 rows of za/zb at the SAME swizzled
// byte offsets as R10's global_load_lds source (bl in bf16-bytes -> bl/2 float
// index). stage_write (T14 split, placed after the phase loop): cvt*SCL with
// RNE __float2bfloat16 (bit-identical to the old convert kernel) and
// ds_write_b128 to the LINEAR LDS address global_load_lds used -> identical
// LDS contents, read side unchanged, swizzle still conflict-free.
__device__ __forceinline__ void stage_load(const float* __restrict__ za,
                                           const float* __restrict__ zb,
                                           int C0, int wave, int lane,
                                           float4 (&SL)[4][2]) {
#pragma unroll
    for (int i = 0; i < 4; ++i) {
        const int chunk = wave * 4 + i;              // 16 chunks of 1 KB (bf16)
        const int r = (chunk << 2) + (lane >> 4);    // col 0..63 of half-tile
        const int bl = ((lane & 15) ^ (r & 15)) << 4;  // swizzled byte-in-bf16-row
        const int r4 = C0 + r;                       // global z row 0..16383
        const float* base = (r4 < Bh ? za : zb) + (size_t)(r4 & (Bh - 1)) * Dd + (bl >> 1);
        SL[i][0] = *(const float4*)(base);
        SL[i][1] = *(const float4*)(base + 4);
    }
}

__device__ __forceinline__ void stage_write(ushort* lbuf, int wave, int lane,
                                            const float4 (&SL)[4][2]) {
#pragma unroll
    for (int i = 0; i < 4; ++i) {
        const int chunk = wave * 4 + i;
        union { ushort u[8]; bf16x8 v; } P;
#pragma unroll
        for (int h = 0; h < 2; ++h) {
            union { float4 v; float f[4]; } X; X.v = SL[i][h];
#pragma unroll
            for (int k = 0; k < 4; ++k) {
                union { __hip_bfloat16 b; ushort s; } cv;
                cv.b = __float2bfloat16(X.f[k] * SCL);
                P.u[h * 4 + k] = cv.s;
            }
        }
        // linear LDS dest (chunk*1KB + lane*16B), exactly global_load_lds' layout
        *(bf16x8*)(lbuf + (chunk << 9) + (lane << 3)) = P.v;
    }
}

// ---- single fused kernel: convert-in-stage + R10 main + last-block finalize.
// R10 post-mortem: total-main = ~50 us across ALL rounds (3-kernel chain,
// ~10-18 us/dispatch overhead) — now the 2nd-largest line item after the
// skeleton. This folds everything into one dispatch + one memset.
// Cross-XCD correctness: producers end with threadfence -> atomicAdd(counter)
// (release); the last-ticket block re-fences (acquire) and reads rowsum /
// pospair with agent-scope atomic loads; pospair is written with agent-scope
// atomic stores (plain stores could sit in a non-coherent per-XCD L2).
__global__ __launch_bounds__(256) void main_kernel(const float* __restrict__ za,
                                                   const float* __restrict__ zb,
                                                   float* __restrict__ rowsum,
                                                   float* __restrict__ pospair,
                                                   int* __restrict__ counter,
                                                   float* __restrict__ out) {
    __shared__ ushort ldsb[2][8192];      // 2 x 16 KB B half-tile double buffer
    __shared__ int sh_ticket;

    const int tid = threadIdx.x;
    const int wave = tid >> 6;
    const int lane = tid & 63;
    const int q = lane >> 4;        // quad: 0..3
    const int c = lane & 15;        // 0..15
    const int g0 = blockIdx.x * K_TILES;

    int tr = row_tile_of(g0);
    int ct = 2 * tr + (g0 - tr * (257 - tr));   // col half-tile 0..255

    // per-lane swizzled LDS fragment offsets: logical 16B-unit (q+4kt) in row c
    int O[4];
#pragma unroll
    for (int kt = 0; kt < 4; ++kt) O[kt] = (c << 8) + ((((q + 4 * kt) ^ c)) << 4);

    bf16x8 afrag[2][4];
    float rs[2][4];
#pragma unroll
    for (int s = 0; s < 2; ++s)
#pragma unroll
        for (int r = 0; r < 4; ++r) rs[s][r] = 0.f;

    const f32x4 Z4 = {0.f, 0.f, 0.f, 0.f};

    float csumP[4];
    int C0P = 0;
    bool pendP = false;
    int cur_tr = -1, rowW = 0, cur = 0;

    float4 SL[4][2];
    // prologue: stage tile 0 (load -> cvt -> write -> barrier)
    stage_load(za, zb, ct << 6, wave, lane, SL);
    stage_write(&ldsb[0][0], wave, lane, SL);
    __syncthreads();

    for (int j = 0; j < K_TILES; ++j) {
        const int C0 = ct << 6;                 // column base (64-wide)
        const bool diag = ((ct >> 1) == tr);    // inside the diagonal 128x128

        if (tr != cur_tr) {                 // row-panel change: flush + reload A
            if (cur_tr >= 0) flush_rs(rowsum, rowW, rs, q, c);
            cur_tr = tr;
            rowW = (tr << 7) + wave * 32;   // this wave's 32-row base
#pragma unroll
            for (int s = 0; s < 2; ++s) {
                const int row = rowW + s * 16 + c;
                const float* ap = (row < Bh ? za : zb) + (size_t)(row & (Bh - 1)) * Dd;
#pragma unroll
                for (int kt = 0; kt < 4; ++kt) {
                    union { float4 v; float f[4]; } X0, X1;
                    X0.v = *(const float4*)(ap + kt * 32 + q * 8);
                    X1.v = *(const float4*)(ap + kt * 32 + q * 8 + 4);
                    union { ushort u[8]; bf16x8 v; } P;
#pragma unroll
                    for (int k = 0; k < 4; ++k) {
                        union { __hip_bfloat16 b; ushort s; } c0, c1;
                        c0.b = __float2bfloat16(X0.f[k] * SCL);
                        c1.b = __float2bfloat16(X1.f[k] * SCL);
                        P.u[k] = c0.s; P.u[4 + k] = c1.s;
                    }
                    afrag[s][kt] = P.v;
                }
            }
        }

        // deferred col-credit flush from previous half-tile
        if (pendP) { colflush(rowsum, csumP, C0P, lane, c); pendP = false; }

        // next half-tile coords + issue its stage LOADS now (latency hides
        // under the phase loop; cvt+ds_write happen after, T14 split)
        int trN = tr, ctN = ct + 1;
        if (ctN == 256) { trN = tr + 1; ctN = 2 * trN; }
        if (j + 1 < K_TILES) stage_load(za, zb, ctN << 6, wave, lane, SL);

        const char* lb = (const char*)&ldsb[cur][0];
        float csum[4];
#pragma unroll
        for (int st = 0; st < 4; ++st) csum[st] = 0.f;

        // ---- acc-pipelined phase loop: 5 phases over 4 st's (R8 schedule).
        f32x4 acc[2][2];
#pragma unroll
        for (int st = 0; st < 5; ++st) {
            const int p = st & 1;
            if (st < 4) {
                bf16x8 bcur[4];
#pragma unroll
                for (int kt = 0; kt < 4; ++kt)
                    bcur[kt] = *(const bf16x8*)(lb + O[kt] + st * 4096);
#pragma unroll
                for (int s = 0; s < 2; ++s)
                    acc[p][s] = __builtin_amdgcn_mfma_f32_16x16x32_bf16(afrag[s][0], bcur[0], Z4, 0, 0, 0);
#pragma unroll
                for (int kt = 1; kt < 4; ++kt) {
#pragma unroll
                    for (int s = 0; s < 2; ++s)
                        acc[p][s] = __builtin_amdgcn_mfma_f32_16x16x32_bf16(afrag[s][kt], bcur[kt], acc[p][s], 0, 0, 0);
                }
            }
            if (st > 0) {
                const int stP = st - 1;         // phase being finished
                const int pp = p ^ 1;
                const int gc0 = C0 + stP * 16;
#pragma unroll
                for (int s = 0; s < 2; ++s) {
                    const int R = rowW + s * 16;
                    float sp[4];
#pragma unroll
                    for (int r = 0; r < 4; ++r) {
                        float u = acc[pp][s][r];
                        // softplus scaled by log2e: max(u,0) + log2(1 + 2^-|u|)
                        float e = __builtin_amdgcn_exp2f(-fabsf(u));
                        sp[r] = fmaxf(u, 0.f) + __builtin_amdgcn_logf(1.f + e);
                    }
                    if (diag && gc0 == R) {               // zero self-similarity
#pragma unroll
                        for (int r = 0; r < 4; ++r)
                            if (c == q * 4 + r) sp[r] = 0.f;
                    }
                    if (gc0 == (R ^ Bh)) {                // positive-pair subtile
#pragma unroll
                        for (int r = 0; r < 4; ++r)
                            if (c == q * 4 + r)
                                __hip_atomic_store(&pospair[R + q * 4 + r], sp[r],
                                                   __ATOMIC_RELAXED, __HIP_MEMORY_SCOPE_AGENT);
                    }
#pragma unroll
                    for (int r = 0; r < 4; ++r) rs[s][r] += sp[r];
                    if (!diag) csum[stP] += (sp[0] + sp[1]) + (sp[2] + sp[3]);
                }
            }
        }

        if (!diag) {    // defer the col-credit atomics past the barrier
#pragma unroll
            for (int st = 0; st < 4; ++st) csumP[st] = csum[st];
            C0P = C0;
            pendP = true;
        }

        // write the prefetched half-tile (compiler inserts the vmcnt for SL)
        if (j + 1 < K_TILES) stage_write(&ldsb[cur ^ 1][0], wave, lane, SL);

        __syncthreads();
        cur ^= 1;
        tr = trN;
        ct = ctN;
    }

    if (pendP) colflush(rowsum, csumP, C0P, lane, c);
    if (cur_tr >= 0) flush_rs(rowsum, rowW, rs, q, c);

    // ---- last-block finalize (release/acquire via fences around counter) ----
    __threadfence();                                   // release my stores/atomics
    __syncthreads();
    if (tid == 0) sh_ticket = atomicAdd(counter, 1);
    __syncthreads();
    if (sh_ticket == N_BLOCKS - 1) {
        __threadfence();                               // acquire
        float acc = 0.f;
        for (int i = tid; i < Nn; i += 256) {
            float rsv = __hip_atomic_load(&rowsum[i], __ATOMIC_RELAXED, __HIP_MEMORY_SCOPE_AGENT);
            float ppv = __hip_atomic_load(&pospair[i & (Bh - 1)], __ATOMIC_RELAXED, __HIP_MEMORY_SCOPE_AGENT);
            float denom = fmaxf(LN2 * rsv, EPS);
            float sp = fmaxf(LN2 * ppv, EPS);
            acc += __logf(sp) - __logf(denom);
        }
#pragma unroll
        for (int m = 1; m < 64; m <<= 1) acc += __shfl_xor(acc, m);
        float* red = (float*)&ldsb[0][0];              // reuse LDS as scratch
        __syncthreads();
        if (lane == 0) red[wave] = acc;
        __syncthreads();
        if (tid == 0)
            out[0] = -(red[0] + red[1] + red[2] + red[3]) / (float)Nn;
    }
}

extern "C" void kernel_launch(void* const* d_in, const int* in_sizes, int n_in,
                              void* d_out, int out_size, void* d_ws, size_t ws_size,
                              hipStream_t stream) {
    const float* za = (const float*)d_in[0];
    const float* zb = (const float*)d_in[1];

    // workspace layout: rowsum (16384 f) | counter+pad (64 f) | pospair (8192 f)
    float* rowsum = (float*)d_ws;
    int* counter = (int*)(rowsum + Nn);
    float* pospair = rowsum + Nn + 64;
    float* out = (float*)d_out;

    // zero rowsum + counter (single memset; graph-capturable)
    hipMemsetAsync(rowsum, 0, (size_t)(Nn + 64) * sizeof(float), stream);
    main_kernel<<<N_BLOCKS, 256, 0, stream>>>(za, zb, rowsum, pospair, counter, out);
}

// Round 12
// 227.223 us; speedup vs baseline: 1.2734x; 1.2734x over previous
//
#include <hip/hip_runtime.h>
#include <hip/hip_bf16.h>

// Problem constants (B=8192, D=128 from reference setup_inputs)
constexpr int Bh = 8192;
constexpr int Nn = 16384;   // 2*B
constexpr int Dd = 128;
constexpr float EPS = 1e-8f;
constexpr float LN2 = 0.69314718056f;

// Geometry (R10, best measured): 128-row x 64-col half-tiles, 16 KB staged B,
// 32 KB LDS dbuf. cum2(t) = t*(257-t); total 128*129 = 16512.
constexpr int K_TILES = 16;         // half-tiles per block
constexpr int N_TILES = 16512;
constexpr int N_BLOCKS = N_TILES / K_TILES;   // 1032, exact

typedef short bf16x8 __attribute__((ext_vector_type(8)));
typedef float f32x4 __attribute__((ext_vector_type(4)));

// ---- Kernel 1: fp32 -> bf16 z buffer (4 MB, per-XCD-L2-resident: R11 proved
// this buffer is load-bearing — staging fp32 directly was a 7.7x FETCH blowup).
// Also zeroes rowsum and the finalize ticket counter.
__global__ __launch_bounds__(256) void convert_kernel(const float4* __restrict__ za,
                                                      const float4* __restrict__ zb,
                                                      ushort* __restrict__ z,
                                                      float* __restrict__ rowsum,
                                                      int* __restrict__ counter) {
    const int t = blockIdx.x * 256 + threadIdx.x;        // 0 .. 524287
    constexpr int Q = (Bh * Dd) / 4;                     // 262144 float4 per input
    const float SCL = 1.69864363f;                       // sqrt(2 * 1.4426950409)
    float4 v = (t < Q) ? za[t] : zb[t - Q];
    union { ushort4 u4; __hip_bfloat16 h[4]; } cv;
    cv.h[0] = __float2bfloat16(v.x * SCL);
    cv.h[1] = __float2bfloat16(v.y * SCL);
    cv.h[2] = __float2bfloat16(v.z * SCL);
    cv.h[3] = __float2bfloat16(v.w * SCL);
    ((ushort4*)z)[t] = cv.u4;
    if (t < Nn) rowsum[t] = 0.f;
    if (t == 0) counter[0] = 0;
}

// half-tile index g -> row tile t: largest t with cum2(t) = t*(257-t) <= g
__device__ __forceinline__ int row_tile_of(int g) {
    int t = (int)((257.0f - sqrtf((float)(66049 - 4 * g))) * 0.5f);
    t = t < 0 ? 0 : (t > 127 ? 127 : t);
    while (t * (257 - t) > g) --t;
    while ((t + 1) * (256 - t) <= g) ++t;
    return t;
}

// row-credit flush: reduce rs over the 16 col-lanes, one atomic per row
__device__ __forceinline__ void flush_rs(float* __restrict__ rowsum, int rowW,
                                         float (&rs)[2][4], int q, int c) {
#pragma unroll
    for (int s = 0; s < 2; ++s)
#pragma unroll
        for (int r = 0; r < 4; ++r) {
            float v = rs[s][r];
            v += __shfl_xor(v, 1);
            v += __shfl_xor(v, 2);
            v += __shfl_xor(v, 4);
            v += __shfl_xor(v, 8);
            if (c == 0) atomicAdd(&rowsum[rowW + s * 16 + q * 4 + r], v);
            rs[s][r] = 0.f;
        }
}

// col-credit flush (deferred one half-tile): reduce over q, one atomic per col
__device__ __forceinline__ void colflush(float* __restrict__ rowsum,
                                         float (&csumP)[4], int C0P, int lane, int c) {
#pragma unroll
    for (int st = 0; st < 4; ++st) {
        float v = csumP[st];
        v += __shfl_xor(v, 16);
        v += __shfl_xor(v, 32);
        if (lane < 16) atomicAdd(&rowsum[C0P + st * 16 + c], v);
    }
}

// Stage one 64-col x 128-K bf16 B half-tile (16 KB) into LDS via
// global_load_lds width-16, XOR-swizzled via the GLOBAL source address (m173).
__device__ __forceinline__ void stage_tile(const ushort* __restrict__ z, ushort* lbuf,
                                           int C0, int wave, int lane) {
#pragma unroll
    for (int i = 0; i < 4; ++i) {
        const int chunk = wave * 4 + i;              // 16 chunks of 1 KB
        const int r = (chunk << 2) + (lane >> 4);    // col 0..63 of this half-tile
        const int bl = ((lane & 15) ^ (r & 15)) << 4;  // swizzled byte-in-row
        const char* gp = (const char*)z + (((size_t)(C0 + r)) << 8) + bl;
        ushort* lp = lbuf + (chunk << 9);            // wave-uniform LDS base
        __builtin_amdgcn_global_load_lds((const __attribute__((address_space(1))) void*)gp,
                                         (__attribute__((address_space(3))) void*)lp,
                                         16, 0, 0);
    }
}

// ---- Kernel 2: R10 main (best measured, 114.5 us) + last-block finalize
// (the HALF of R11's fusion that worked — fence/ticket verified correct).
// Saves one dispatch (~15 us) and the finalize kernel's execution.
// Cross-XCD correctness: pospair written with agent-scope atomic stores;
// producers threadfence->ticket (release); last block re-fences (acquire)
// and reads rowsum/pospair with agent-scope atomic loads.
__global__ __launch_bounds__(256) void main_kernel(const ushort* __restrict__ z,
                                                   float* __restrict__ rowsum,
                                                   float* __restrict__ pospair,
                                                   int* __restrict__ counter,
                                                   float* __restrict__ out) {
    __shared__ ushort ldsb[2][8192];      // 2 x 16 KB B half-tile double buffer

    const int tid = threadIdx.x;
    const int wave = tid >> 6;
    const int lane = tid & 63;
    const int q = lane >> 4;        // quad: 0..3
    const int c = lane & 15;        // 0..15
    const int g0 = blockIdx.x * K_TILES;

    int tr = row_tile_of(g0);
    int ct = 2 * tr + (g0 - tr * (257 - tr));   // col half-tile 0..255

    // per-lane swizzled LDS fragment offsets: logical 16B-unit (q+4kt) in row c
    int O[4];
#pragma unroll
    for (int kt = 0; kt < 4; ++kt) O[kt] = (c << 8) + ((((q + 4 * kt) ^ c)) << 4);

    bf16x8 afrag[2][4];
    float rs[2][4];
#pragma unroll
    for (int s = 0; s < 2; ++s)
#pragma unroll
        for (int r = 0; r < 4; ++r) rs[s][r] = 0.f;

    const f32x4 Z4 = {0.f, 0.f, 0.f, 0.f};

    float csumP[4];
    int C0P = 0;
    bool pendP = false;
    int cur_tr = -1, rowW = 0, cur = 0;

    stage_tile(z, &ldsb[0][0], ct << 6, wave, lane);
    __syncthreads();

    for (int j = 0; j < K_TILES; ++j) {
        const int C0 = ct << 6;                 // column base (64-wide)
        const bool diag = ((ct >> 1) == tr);    // inside the diagonal 128x128

        if (tr != cur_tr) {                 // row-panel change: flush + reload A
            if (cur_tr >= 0) flush_rs(rowsum, rowW, rs, q, c);
            cur_tr = tr;
            rowW = (tr << 7) + wave * 32;   // this wave's 32-row base
#pragma unroll
            for (int s = 0; s < 2; ++s) {
                const ushort* ap = z + (size_t)(rowW + s * 16 + c) * Dd;
#pragma unroll
                for (int kt = 0; kt < 4; ++kt)
                    afrag[s][kt] = *(const bf16x8*)(ap + kt * 32 + q * 8);
            }
        }

        // deferred col-credit flush from previous half-tile
        if (pendP) { colflush(rowsum, csumP, C0P, lane, c); pendP = false; }

        // next half-tile coords + prefetch-stage into the other buffer
        int trN = tr, ctN = ct + 1;
        if (ctN == 256) { trN = tr + 1; ctN = 2 * trN; }
        if (j + 1 < K_TILES) stage_tile(z, &ldsb[cur ^ 1][0], ctN << 6, wave, lane);

        const char* lb = (const char*)&ldsb[cur][0];
        float csum[4];
#pragma unroll
        for (int st = 0; st < 4; ++st) csum[st] = 0.f;

        // ---- acc-pipelined phase loop: 5 phases over 4 st's (R8 schedule).
        f32x4 acc[2][2];
#pragma unroll
        for (int st = 0; st < 5; ++st) {
            const int p = st & 1;
            if (st < 4) {
                bf16x8 bcur[4];
#pragma unroll
                for (int kt = 0; kt < 4; ++kt)
                    bcur[kt] = *(const bf16x8*)(lb + O[kt] + st * 4096);
#pragma unroll
                for (int s = 0; s < 2; ++s)
                    acc[p][s] = __builtin_amdgcn_mfma_f32_16x16x32_bf16(afrag[s][0], bcur[0], Z4, 0, 0, 0);
#pragma unroll
                for (int kt = 1; kt < 4; ++kt) {
#pragma unroll
                    for (int s = 0; s < 2; ++s)
                        acc[p][s] = __builtin_amdgcn_mfma_f32_16x16x32_bf16(afrag[s][kt], bcur[kt], acc[p][s], 0, 0, 0);
                }
            }
            if (st > 0) {
                const int stP = st - 1;         // phase being finished
                const int pp = p ^ 1;
                const int gc0 = C0 + stP * 16;
#pragma unroll
                for (int s = 0; s < 2; ++s) {
                    const int R = rowW + s * 16;
                    float sp[4];
#pragma unroll
                    for (int r = 0; r < 4; ++r) {
                        float u = acc[pp][s][r];
                        // softplus scaled by log2e: max(u,0) + log2(1 + 2^-|u|)
                        float e = __builtin_amdgcn_exp2f(-fabsf(u));
                        sp[r] = fmaxf(u, 0.f) + __builtin_amdgcn_logf(1.f + e);
                    }
                    if (diag && gc0 == R) {               // zero self-similarity
#pragma unroll
                        for (int r = 0; r < 4; ++r)
                            if (c == q * 4 + r) sp[r] = 0.f;
                    }
                    if (gc0 == (R ^ Bh)) {                // positive-pair subtile
#pragma unroll
                        for (int r = 0; r < 4; ++r)
                            if (c == q * 4 + r)
                                __hip_atomic_store(&pospair[R + q * 4 + r], sp[r],
                                                   __ATOMIC_RELAXED, __HIP_MEMORY_SCOPE_AGENT);
                    }
#pragma unroll
                    for (int r = 0; r < 4; ++r) rs[s][r] += sp[r];
                    if (!diag) csum[stP] += (sp[0] + sp[1]) + (sp[2] + sp[3]);
                }
            }
        }

        if (!diag) {    // defer the col-credit atomics past the barrier
#pragma unroll
            for (int st = 0; st < 4; ++st) csumP[st] = csum[st];
            C0P = C0;
            pendP = true;
        }

        __syncthreads();        // drains vmcnt(0): stage + atomics all a phase old
        cur ^= 1;
        tr = trN;
        ct = ctN;
    }

    if (pendP) colflush(rowsum, csumP, C0P, lane, c);
    if (cur_tr >= 0) flush_rs(rowsum, rowW, rs, q, c);

    // ---- last-block finalize (release/acquire via fences around counter) ----
    __threadfence();                                   // release my stores/atomics
    __syncthreads();
    int* shi = (int*)&ldsb[0][0];                      // LDS dead now: reuse
    if (tid == 0) shi[0] = atomicAdd(counter, 1);
    __syncthreads();
    if (shi[0] == N_BLOCKS - 1) {
        __threadfence();                               // acquire
        float acc = 0.f;
        for (int i = tid; i < Nn; i += 256) {
            float rsv = __hip_atomic_load(&rowsum[i], __ATOMIC_RELAXED, __HIP_MEMORY_SCOPE_AGENT);
            float ppv = __hip_atomic_load(&pospair[i & (Bh - 1)], __ATOMIC_RELAXED, __HIP_MEMORY_SCOPE_AGENT);
            float denom = fmaxf(LN2 * rsv, EPS);
            float sp = fmaxf(LN2 * ppv, EPS);
            acc += __logf(sp) - __logf(denom);
        }
#pragma unroll
        for (int m = 1; m < 64; m <<= 1) acc += __shfl_xor(acc, m);
        __syncthreads();                               // all have read shi[0]
        float* red = (float*)&ldsb[0][0];
        if (lane == 0) red[wave] = acc;
        __syncthreads();
        if (tid == 0)
            out[0] = -(red[0] + red[1] + red[2] + red[3]) / (float)Nn;
    }
}

extern "C" void kernel_launch(void* const* d_in, const int* in_sizes, int n_in,
                              void* d_out, int out_size, void* d_ws, size_t ws_size,
                              hipStream_t stream) {
    const float* za = (const float*)d_in[0];
    const float* zb = (const float*)d_in[1];

    // workspace layout: z bf16 (4 MB) | rowsum (16384 f) | counter+pad (64 f) | pospair
    ushort* z = (ushort*)d_ws;
    float* rowsum = (float*)((char*)d_ws + (size_t)Nn * Dd * 2);
    int* counter = (int*)(rowsum + Nn);
    float* pospair = rowsum + Nn + 64;
    float* out = (float*)d_out;

    convert_kernel<<<2048, 256, 0, stream>>>((const float4*)za, (const float4*)zb, z, rowsum, counter);
    main_kernel<<<N_BLOCKS, 256, 0, stream>>>(z, rowsum, pospair, counter, out);
}

// Round 13
// 184.268 us; speedup vs baseline: 1.5702x; 1.2331x over previous
//
#include <hip/hip_runtime.h>
#include <hip/hip_bf16.h>

// Problem constants (B=8192, D=128 from reference setup_inputs)
constexpr int Bh = 8192;
constexpr int Nn = 16384;   // 2*B
constexpr int Dd = 128;
constexpr float EPS = 1e-8f;
constexpr float LN2 = 0.69314718056f;

// Geometry (R10, best measured): 128-row x 64-col half-tiles, 16 KB staged B,
// 32 KB LDS dbuf. cum2(t) = t*(257-t); total 128*129 = 16512.
constexpr int K_TILES = 16;         // half-tiles per block
constexpr int N_TILES = 16512;
constexpr int N_BLOCKS = N_TILES / K_TILES;   // 1032, exact

typedef short bf16x8 __attribute__((ext_vector_type(8)));
typedef float f32x4 __attribute__((ext_vector_type(4)));

// ---- Kernel 1: fp32 -> bf16 z buffer (4 MB, per-XCD-L2-resident: R11 proved
// this buffer is load-bearing). Also zeroes rowsum and the ticket counter.
__global__ __launch_bounds__(256) void convert_kernel(const float4* __restrict__ za,
                                                      const float4* __restrict__ zb,
                                                      ushort* __restrict__ z,
                                                      float* __restrict__ rowsum,
                                                      int* __restrict__ counter) {
    const int t = blockIdx.x * 256 + threadIdx.x;        // 0 .. 524287
    constexpr int Q = (Bh * Dd) / 4;                     // 262144 float4 per input
    const float SCL = 1.69864363f;                       // sqrt(2 * 1.4426950409)
    float4 v = (t < Q) ? za[t] : zb[t - Q];
    union { ushort4 u4; __hip_bfloat16 h[4]; } cv;
    cv.h[0] = __float2bfloat16(v.x * SCL);
    cv.h[1] = __float2bfloat16(v.y * SCL);
    cv.h[2] = __float2bfloat16(v.z * SCL);
    cv.h[3] = __float2bfloat16(v.w * SCL);
    ((ushort4*)z)[t] = cv.u4;
    if (t < Nn) rowsum[t] = 0.f;
    if (t == 0) counter[0] = 0;
}

// half-tile index g -> row tile t: largest t with cum2(t) = t*(257-t) <= g
__device__ __forceinline__ int row_tile_of(int g) {
    int t = (int)((257.0f - sqrtf((float)(66049 - 4 * g))) * 0.5f);
    t = t < 0 ? 0 : (t > 127 ? 127 : t);
    while (t * (257 - t) > g) --t;
    while ((t + 1) * (256 - t) <= g) ++t;
    return t;
}

// row-credit flush: reduce rs over the 16 col-lanes, one atomic per row
__device__ __forceinline__ void flush_rs(float* __restrict__ rowsum, int rowW,
                                         float (&rs)[2][4], int q, int c) {
#pragma unroll
    for (int s = 0; s < 2; ++s)
#pragma unroll
        for (int r = 0; r < 4; ++r) {
            float v = rs[s][r];
            v += __shfl_xor(v, 1);
            v += __shfl_xor(v, 2);
            v += __shfl_xor(v, 4);
            v += __shfl_xor(v, 8);
            if (c == 0) atomicAdd(&rowsum[rowW + s * 16 + q * 4 + r], v);
            rs[s][r] = 0.f;
        }
}

// col-credit flush (deferred one half-tile): reduce over q, one atomic per col
__device__ __forceinline__ void colflush(float* __restrict__ rowsum,
                                         float (&csumP)[4], int C0P, int lane, int c) {
#pragma unroll
    for (int st = 0; st < 4; ++st) {
        float v = csumP[st];
        v += __shfl_xor(v, 16);
        v += __shfl_xor(v, 32);
        if (lane < 16) atomicAdd(&rowsum[C0P + st * 16 + c], v);
    }
}

// Stage one 64-col x 128-K bf16 B half-tile (16 KB) into LDS via
// global_load_lds width-16, XOR-swizzled via the GLOBAL source address (m173).
__device__ __forceinline__ void stage_tile(const ushort* __restrict__ z, ushort* lbuf,
                                           int C0, int wave, int lane) {
#pragma unroll
    for (int i = 0; i < 4; ++i) {
        const int chunk = wave * 4 + i;              // 16 chunks of 1 KB
        const int r = (chunk << 2) + (lane >> 4);    // col 0..63 of this half-tile
        const int bl = ((lane & 15) ^ (r & 15)) << 4;  // swizzled byte-in-row
        const char* gp = (const char*)z + (((size_t)(C0 + r)) << 8) + bl;
        ushort* lp = lbuf + (chunk << 9);            // wave-uniform LDS base
        __builtin_amdgcn_global_load_lds((const __attribute__((address_space(1))) void*)gp,
                                         (__attribute__((address_space(3))) void*)lp,
                                         16, 0, 0);
    }
}

// ---- Kernel 2: R10 main + last-block finalize, NO __threadfence.
// R12 post-mortem: __threadfence() per block = buffer_wbl2 + buffer_inv sc1
// -> each finishing block INVALIDATED its XCD's L2, keeping the 4 MB z
// buffer perpetually cold (main 114.5 -> 179.6 us, same MFMA/VALU absolute
// time, FETCH unchanged -> pure L2->L3 latency stall). The fence is also
// unnecessary: ALL producer writes are device-coherent atomics (rowsum:
// device-scope atomicAdd; pospair: agent-scope atomic store), performed at
// the coherent point and never dirty in L2. Ordering: __syncthreads before
// the ticket emits s_waitcnt vmcnt(0) per wave (barrier drain), so every
// block's atomics have COMPLETED before its ticket increments; the last
// block's agent-scope atomic loads bypass stale caches.
__global__ __launch_bounds__(256) void main_kernel(const ushort* __restrict__ z,
                                                   float* __restrict__ rowsum,
                                                   float* __restrict__ pospair,
                                                   int* __restrict__ counter,
                                                   float* __restrict__ out) {
    __shared__ ushort ldsb[2][8192];      // 2 x 16 KB B half-tile double buffer

    const int tid = threadIdx.x;
    const int wave = tid >> 6;
    const int lane = tid & 63;
    const int q = lane >> 4;        // quad: 0..3
    const int c = lane & 15;        // 0..15
    const int g0 = blockIdx.x * K_TILES;

    int tr = row_tile_of(g0);
    int ct = 2 * tr + (g0 - tr * (257 - tr));   // col half-tile 0..255

    // per-lane swizzled LDS fragment offsets: logical 16B-unit (q+4kt) in row c
    int O[4];
#pragma unroll
    for (int kt = 0; kt < 4; ++kt) O[kt] = (c << 8) + ((((q + 4 * kt) ^ c)) << 4);

    bf16x8 afrag[2][4];
    float rs[2][4];
#pragma unroll
    for (int s = 0; s < 2; ++s)
#pragma unroll
        for (int r = 0; r < 4; ++r) rs[s][r] = 0.f;

    const f32x4 Z4 = {0.f, 0.f, 0.f, 0.f};

    float csumP[4];
    int C0P = 0;
    bool pendP = false;
    int cur_tr = -1, rowW = 0, cur = 0;

    stage_tile(z, &ldsb[0][0], ct << 6, wave, lane);
    __syncthreads();

    for (int j = 0; j < K_TILES; ++j) {
        const int C0 = ct << 6;                 // column base (64-wide)
        const bool diag = ((ct >> 1) == tr);    // inside the diagonal 128x128

        if (tr != cur_tr) {                 // row-panel change: flush + reload A
            if (cur_tr >= 0) flush_rs(rowsum, rowW, rs, q, c);
            cur_tr = tr;
            rowW = (tr << 7) + wave * 32;   // this wave's 32-row base
#pragma unroll
            for (int s = 0; s < 2; ++s) {
                const ushort* ap = z + (size_t)(rowW + s * 16 + c) * Dd;
#pragma unroll
                for (int kt = 0; kt < 4; ++kt)
                    afrag[s][kt] = *(const bf16x8*)(ap + kt * 32 + q * 8);
            }
        }

        // deferred col-credit flush from previous half-tile
        if (pendP) { colflush(rowsum, csumP, C0P, lane, c); pendP = false; }

        // next half-tile coords + prefetch-stage into the other buffer
        int trN = tr, ctN = ct + 1;
        if (ctN == 256) { trN = tr + 1; ctN = 2 * trN; }
        if (j + 1 < K_TILES) stage_tile(z, &ldsb[cur ^ 1][0], ctN << 6, wave, lane);

        const char* lb = (const char*)&ldsb[cur][0];
        float csum[4];
#pragma unroll
        for (int st = 0; st < 4; ++st) csum[st] = 0.f;

        // ---- acc-pipelined phase loop: 5 phases over 4 st's (R8 schedule).
        f32x4 acc[2][2];
#pragma unroll
        for (int st = 0; st < 5; ++st) {
            const int p = st & 1;
            if (st < 4) {
                bf16x8 bcur[4];
#pragma unroll
                for (int kt = 0; kt < 4; ++kt)
                    bcur[kt] = *(const bf16x8*)(lb + O[kt] + st * 4096);
#pragma unroll
                for (int s = 0; s < 2; ++s)
                    acc[p][s] = __builtin_amdgcn_mfma_f32_16x16x32_bf16(afrag[s][0], bcur[0], Z4, 0, 0, 0);
#pragma unroll
                for (int kt = 1; kt < 4; ++kt) {
#pragma unroll
                    for (int s = 0; s < 2; ++s)
                        acc[p][s] = __builtin_amdgcn_mfma_f32_16x16x32_bf16(afrag[s][kt], bcur[kt], acc[p][s], 0, 0, 0);
                }
            }
            if (st > 0) {
                const int stP = st - 1;         // phase being finished
                const int pp = p ^ 1;
                const int gc0 = C0 + stP * 16;
#pragma unroll
                for (int s = 0; s < 2; ++s) {
                    const int R = rowW + s * 16;
                    float sp[4];
#pragma unroll
                    for (int r = 0; r < 4; ++r) {
                        float u = acc[pp][s][r];
                        // softplus scaled by log2e: max(u,0) + log2(1 + 2^-|u|)
                        float e = __builtin_amdgcn_exp2f(-fabsf(u));
                        sp[r] = fmaxf(u, 0.f) + __builtin_amdgcn_logf(1.f + e);
                    }
                    if (diag && gc0 == R) {               // zero self-similarity
#pragma unroll
                        for (int r = 0; r < 4; ++r)
                            if (c == q * 4 + r) sp[r] = 0.f;
                    }
                    if (gc0 == (R ^ Bh)) {                // positive-pair subtile
#pragma unroll
                        for (int r = 0; r < 4; ++r)
                            if (c == q * 4 + r)
                                __hip_atomic_store(&pospair[R + q * 4 + r], sp[r],
                                                   __ATOMIC_RELAXED, __HIP_MEMORY_SCOPE_AGENT);
                    }
#pragma unroll
                    for (int r = 0; r < 4; ++r) rs[s][r] += sp[r];
                    if (!diag) csum[stP] += (sp[0] + sp[1]) + (sp[2] + sp[3]);
                }
            }
        }

        if (!diag) {    // defer the col-credit atomics past the barrier
#pragma unroll
            for (int st = 0; st < 4; ++st) csumP[st] = csum[st];
            C0P = C0;
            pendP = true;
        }

        __syncthreads();        // drains vmcnt(0): stage + atomics all a phase old
        cur ^= 1;
        tr = trN;
        ct = ctN;
    }

    if (pendP) colflush(rowsum, csumP, C0P, lane, c);
    if (cur_tr >= 0) flush_rs(rowsum, rowW, rs, q, c);

    // ---- last-block finalize (NO fences; see header comment) ----
    __syncthreads();                       // barrier drain: all my atomics done
    int* shi = (int*)&ldsb[0][0];          // LDS dead now: reuse
    if (tid == 0) shi[0] = atomicAdd(counter, 1);
    __syncthreads();
    if (shi[0] == N_BLOCKS - 1) {
        float acc = 0.f;
        for (int i = tid; i < Nn; i += 256) {
            float rsv = __hip_atomic_load(&rowsum[i], __ATOMIC_RELAXED, __HIP_MEMORY_SCOPE_AGENT);
            float ppv = __hip_atomic_load(&pospair[i & (Bh - 1)], __ATOMIC_RELAXED, __HIP_MEMORY_SCOPE_AGENT);
            float denom = fmaxf(LN2 * rsv, EPS);
            float sp = fmaxf(LN2 * ppv, EPS);
            acc += __logf(sp) - __logf(denom);
        }
#pragma unroll
        for (int m = 1; m < 64; m <<= 1) acc += __shfl_xor(acc, m);
        __syncthreads();                   // all have read shi[0]
        float* red = (float*)&ldsb[0][0];
        if (lane == 0) red[wave] = acc;
        __syncthreads();
        if (tid == 0)
            out[0] = -(red[0] + red[1] + red[2] + red[3]) / (float)Nn;
    }
}

extern "C" void kernel_launch(void* const* d_in, const int* in_sizes, int n_in,
                              void* d_out, int out_size, void* d_ws, size_t ws_size,
                              hipStream_t stream) {
    const float* za = (const float*)d_in[0];
    const float* zb = (const float*)d_in[1];

    // workspace layout: z bf16 (4 MB) | rowsum (16384 f) | counter+pad (64 f) | pospair
    ushort* z = (ushort*)d_ws;
    float* rowsum = (float*)((char*)d_ws + (size_t)Nn * Dd * 2);
    int* counter = (int*)(rowsum + Nn);
    float* pospair = rowsum + Nn + 64;
    float* out = (float*)d_out;

    convert_kernel<<<2048, 256, 0, stream>>>((const float4*)za, (const float4*)zb, z, rowsum, counter);
    main_kernel<<<N_BLOCKS, 256, 0, stream>>>(z, rowsum, pospair, counter, out);
}

// Round 14
// 181.140 us; speedup vs baseline: 1.5974x; 1.0173x over previous
//
#include <hip/hip_runtime.h>
#include <hip/hip_bf16.h>

// Problem constants (B=8192, D=128 from reference setup_inputs)
constexpr int Bh = 8192;
constexpr int Nn = 16384;   // 2*B
constexpr int Dd = 128;
constexpr float EPS = 1e-8f;
constexpr float LN2 = 0.69314718056f;

// Geometry (R10, best measured): 128-row x 64-col half-tiles, 16 KB staged B,
// 32 KB LDS dbuf. cum2(t) = t*(257-t); total 128*129 = 16512.
constexpr int K_TILES = 16;         // half-tiles per block
constexpr int N_TILES = 16512;
constexpr int N_BLOCKS = N_TILES / K_TILES;   // 1032, exact

typedef short bf16x8 __attribute__((ext_vector_type(8)));
typedef float f32x4 __attribute__((ext_vector_type(4)));

// ---- Kernel 1: fp32 -> bf16 z buffer (4 MB, per-XCD-L2-resident: R11 proved
// this buffer is load-bearing). Also zeroes rowsum, ticket counter, possum.
__global__ __launch_bounds__(256) void convert_kernel(const float4* __restrict__ za,
                                                      const float4* __restrict__ zb,
                                                      ushort* __restrict__ z,
                                                      float* __restrict__ rowsum,
                                                      int* __restrict__ counter,
                                                      float* __restrict__ possum) {
    const int t = blockIdx.x * 256 + threadIdx.x;        // 0 .. 524287
    constexpr int Q = (Bh * Dd) / 4;                     // 262144 float4 per input
    const float SCL = 1.69864363f;                       // sqrt(2 * 1.4426950409)
    float4 v = (t < Q) ? za[t] : zb[t - Q];
    union { ushort4 u4; __hip_bfloat16 h[4]; } cv;
    cv.h[0] = __float2bfloat16(v.x * SCL);
    cv.h[1] = __float2bfloat16(v.y * SCL);
    cv.h[2] = __float2bfloat16(v.z * SCL);
    cv.h[3] = __float2bfloat16(v.w * SCL);
    ((ushort4*)z)[t] = cv.u4;
    if (t < Nn) rowsum[t] = 0.f;
    if (t == 0) { counter[0] = 0; possum[0] = 0.f; }
}

// half-tile index g -> row tile t: largest t with cum2(t) = t*(257-t) <= g
__device__ __forceinline__ int row_tile_of(int g) {
    int t = (int)((257.0f - sqrtf((float)(66049 - 4 * g))) * 0.5f);
    t = t < 0 ? 0 : (t > 127 ? 127 : t);
    while (t * (257 - t) > g) --t;
    while ((t + 1) * (256 - t) <= g) ++t;
    return t;
}

// row-credit flush: reduce rs over the 16 col-lanes, one atomic per row
__device__ __forceinline__ void flush_rs(float* __restrict__ rowsum, int rowW,
                                         float (&rs)[2][4], int q, int c) {
#pragma unroll
    for (int s = 0; s < 2; ++s)
#pragma unroll
        for (int r = 0; r < 4; ++r) {
            float v = rs[s][r];
            v += __shfl_xor(v, 1);
            v += __shfl_xor(v, 2);
            v += __shfl_xor(v, 4);
            v += __shfl_xor(v, 8);
            if (c == 0) atomicAdd(&rowsum[rowW + s * 16 + q * 4 + r], v);
            rs[s][r] = 0.f;
        }
}

// col-credit flush (deferred one half-tile): reduce over q, one atomic per col
__device__ __forceinline__ void colflush(float* __restrict__ rowsum,
                                         float (&csumP)[4], int C0P, int lane, int c) {
#pragma unroll
    for (int st = 0; st < 4; ++st) {
        float v = csumP[st];
        v += __shfl_xor(v, 16);
        v += __shfl_xor(v, 32);
        if (lane < 16) atomicAdd(&rowsum[C0P + st * 16 + c], v);
    }
}

// Stage one 64-col x 128-K bf16 B half-tile (16 KB) into LDS via
// global_load_lds width-16, XOR-swizzled via the GLOBAL source address (m173).
__device__ __forceinline__ void stage_tile(const ushort* __restrict__ z, ushort* lbuf,
                                           int C0, int wave, int lane) {
#pragma unroll
    for (int i = 0; i < 4; ++i) {
        const int chunk = wave * 4 + i;              // 16 chunks of 1 KB
        const int r = (chunk << 2) + (lane >> 4);    // col 0..63 of this half-tile
        const int bl = ((lane & 15) ^ (r & 15)) << 4;  // swizzled byte-in-row
        const char* gp = (const char*)z + (((size_t)(C0 + r)) << 8) + bl;
        ushort* lp = lbuf + (chunk << 9);            // wave-uniform LDS base
        __builtin_amdgcn_global_load_lds((const __attribute__((address_space(1))) void*)gp,
                                         (__attribute__((address_space(3))) void*)lp,
                                         16, 0, 0);
    }
}

// ---- Kernel 2: R10 main + last-block finalize (no fences), NO pospair buffer.
// R13 post-mortem: the in-loop agent-scope atomic store for pospair cost
// +21.9 us — atomics are scheduling-opaque, so each st's epilogue contained a
// codegen fence splitting the ds_read/MFMA/VALU scheduling regions. R14:
// Sum_i log(sp_pos_i) = 2*Sum_{i<B} log(sp_pos_i), and each positive-pair
// element is computed exactly ONCE (its subtile is always above-diagonal),
// so accumulate log(max(LN2*sp,EPS)) into a REGISTER on the (wave-uniform,
// <=2 per row-panel) hit and atomicAdd once per wave at kernel end. Inner
// loop now has ZERO stores. Fences remain unnecessary: all cross-block data
// (rowsum, possum) is written solely with device-coherent atomicAdd; the
// pre-ticket __syncthreads drains vmcnt(0) so atomics complete before the
// ticket; the last block reads via agent-scope atomic loads.
__global__ __launch_bounds__(256) void main_kernel(const ushort* __restrict__ z,
                                                   float* __restrict__ rowsum,
                                                   int* __restrict__ counter,
                                                   float* __restrict__ possum,
                                                   float* __restrict__ out) {
    __shared__ ushort ldsb[2][8192];      // 2 x 16 KB B half-tile double buffer

    const int tid = threadIdx.x;
    const int wave = tid >> 6;
    const int lane = tid & 63;
    const int q = lane >> 4;        // quad: 0..3
    const int c = lane & 15;        // 0..15
    const int g0 = blockIdx.x * K_TILES;

    int tr = row_tile_of(g0);
    int ct = 2 * tr + (g0 - tr * (257 - tr));   // col half-tile 0..255

    // per-lane swizzled LDS fragment offsets: logical 16B-unit (q+4kt) in row c
    int O[4];
#pragma unroll
    for (int kt = 0; kt < 4; ++kt) O[kt] = (c << 8) + ((((q + 4 * kt) ^ c)) << 4);

    bf16x8 afrag[2][4];
    float rs[2][4];
#pragma unroll
    for (int s = 0; s < 2; ++s)
#pragma unroll
        for (int r = 0; r < 4; ++r) rs[s][r] = 0.f;

    const f32x4 Z4 = {0.f, 0.f, 0.f, 0.f};

    float pacc = 0.f;               // this lane's positive-pair log contributions
    float csumP[4];
    int C0P = 0;
    bool pendP = false;
    int cur_tr = -1, rowW = 0, cur = 0;

    stage_tile(z, &ldsb[0][0], ct << 6, wave, lane);
    __syncthreads();

    for (int j = 0; j < K_TILES; ++j) {
        const int C0 = ct << 6;                 // column base (64-wide)
        const bool diag = ((ct >> 1) == tr);    // inside the diagonal 128x128

        if (tr != cur_tr) {                 // row-panel change: flush + reload A
            if (cur_tr >= 0) flush_rs(rowsum, rowW, rs, q, c);
            cur_tr = tr;
            rowW = (tr << 7) + wave * 32;   // this wave's 32-row base
#pragma unroll
            for (int s = 0; s < 2; ++s) {
                const ushort* ap = z + (size_t)(rowW + s * 16 + c) * Dd;
#pragma unroll
                for (int kt = 0; kt < 4; ++kt)
                    afrag[s][kt] = *(const bf16x8*)(ap + kt * 32 + q * 8);
            }
        }

        // deferred col-credit flush from previous half-tile
        if (pendP) { colflush(rowsum, csumP, C0P, lane, c); pendP = false; }

        // next half-tile coords + prefetch-stage into the other buffer
        int trN = tr, ctN = ct + 1;
        if (ctN == 256) { trN = tr + 1; ctN = 2 * trN; }
        if (j + 1 < K_TILES) stage_tile(z, &ldsb[cur ^ 1][0], ctN << 6, wave, lane);

        const char* lb = (const char*)&ldsb[cur][0];
        float csum[4];
#pragma unroll
        for (int st = 0; st < 4; ++st) csum[st] = 0.f;

        // ---- acc-pipelined phase loop: 5 phases over 4 st's (R8 schedule).
        f32x4 acc[2][2];
#pragma unroll
        for (int st = 0; st < 5; ++st) {
            const int p = st & 1;
            if (st < 4) {
                bf16x8 bcur[4];
#pragma unroll
                for (int kt = 0; kt < 4; ++kt)
                    bcur[kt] = *(const bf16x8*)(lb + O[kt] + st * 4096);
#pragma unroll
                for (int s = 0; s < 2; ++s)
                    acc[p][s] = __builtin_amdgcn_mfma_f32_16x16x32_bf16(afrag[s][0], bcur[0], Z4, 0, 0, 0);
#pragma unroll
                for (int kt = 1; kt < 4; ++kt) {
#pragma unroll
                    for (int s = 0; s < 2; ++s)
                        acc[p][s] = __builtin_amdgcn_mfma_f32_16x16x32_bf16(afrag[s][kt], bcur[kt], acc[p][s], 0, 0, 0);
                }
            }
            if (st > 0) {
                const int stP = st - 1;         // phase being finished
                const int pp = p ^ 1;
                const int gc0 = C0 + stP * 16;
#pragma unroll
                for (int s = 0; s < 2; ++s) {
                    const int R = rowW + s * 16;
                    float sp[4];
#pragma unroll
                    for (int r = 0; r < 4; ++r) {
                        float u = acc[pp][s][r];
                        // softplus scaled by log2e: max(u,0) + log2(1 + 2^-|u|)
                        float e = __builtin_amdgcn_exp2f(-fabsf(u));
                        sp[r] = fmaxf(u, 0.f) + __builtin_amdgcn_logf(1.f + e);
                    }
                    if (diag && gc0 == R) {               // zero self-similarity
#pragma unroll
                        for (int r = 0; r < 4; ++r)
                            if (c == q * 4 + r) sp[r] = 0.f;
                    }
                    if (gc0 == (R ^ Bh)) {                // positive-pair subtile
                        // (wave-uniform branch, hits <=2x per row-panel; R<Bh
                        // guaranteed since R>=Bh would be below-diagonal)
#pragma unroll
                        for (int r = 0; r < 4; ++r)
                            if (c == q * 4 + r)
                                pacc += __logf(fmaxf(LN2 * sp[r], EPS));
                    }
#pragma unroll
                    for (int r = 0; r < 4; ++r) rs[s][r] += sp[r];
                    if (!diag) csum[stP] += (sp[0] + sp[1]) + (sp[2] + sp[3]);
                }
            }
        }

        if (!diag) {    // defer the col-credit atomics past the barrier
#pragma unroll
            for (int st = 0; st < 4; ++st) csumP[st] = csum[st];
            C0P = C0;
            pendP = true;
        }

        __syncthreads();        // drains vmcnt(0): stage + atomics all a phase old
        cur ^= 1;
        tr = trN;
        ct = ctN;
    }

    if (pendP) colflush(rowsum, csumP, C0P, lane, c);
    if (cur_tr >= 0) flush_rs(rowsum, rowW, rs, q, c);

    // positive-pair contribution: wave-reduce pacc, one atomic per wave (x2:
    // each pair element appears twice in the full N-sum)
    {
        float v = pacc;
#pragma unroll
        for (int m = 1; m < 64; m <<= 1) v += __shfl_xor(v, m);
        if (lane == 0 && v != 0.f) atomicAdd(possum, v + v);
    }

    // ---- last-block finalize (no fences; see header comment) ----
    __syncthreads();                       // barrier drain: all my atomics done
    int* shi = (int*)&ldsb[0][0];          // LDS dead now: reuse
    if (tid == 0) shi[0] = atomicAdd(counter, 1);
    __syncthreads();
    if (shi[0] == N_BLOCKS - 1) {
        float acc = 0.f;                   // sum of log(denom_i)
        for (int i = tid; i < Nn; i += 256) {
            float rsv = __hip_atomic_load(&rowsum[i], __ATOMIC_RELAXED, __HIP_MEMORY_SCOPE_AGENT);
            acc += __logf(fmaxf(LN2 * rsv, EPS));
        }
#pragma unroll
        for (int m = 1; m < 64; m <<= 1) acc += __shfl_xor(acc, m);
        __syncthreads();                   // all have read shi[0]
        float* red = (float*)&ldsb[0][0];
        if (lane == 0) red[wave] = acc;
        __syncthreads();
        if (tid == 0) {
            float ps = __hip_atomic_load(possum, __ATOMIC_RELAXED, __HIP_MEMORY_SCOPE_AGENT);
            float sumden = red[0] + red[1] + red[2] + red[3];
            out[0] = (sumden - ps) / (float)Nn;   // = -(possum - sum(log denom))/N
        }
    }
}

extern "C" void kernel_launch(void* const* d_in, const int* in_sizes, int n_in,
                              void* d_out, int out_size, void* d_ws, size_t ws_size,
                              hipStream_t stream) {
    const float* za = (const float*)d_in[0];
    const float* zb = (const float*)d_in[1];

    // workspace layout: z bf16 (4 MB) | rowsum (16384 f) | counter | possum
    ushort* z = (ushort*)d_ws;
    float* rowsum = (float*)((char*)d_ws + (size_t)Nn * Dd * 2);
    int* counter = (int*)(rowsum + Nn);
    float* possum = (float*)(rowsum + Nn + 32);
    float* out = (float*)d_out;

    convert_kernel<<<2048, 256, 0, stream>>>((const float4*)za, (const float4*)zb, z, rowsum, counter, possum);
    main_kernel<<<N_BLOCKS, 256, 0, stream>>>(z, rowsum, counter, possum, out);
}

// Round 15
// 167.096 us; speedup vs baseline: 1.7316x; 1.0840x over previous
//
#include <hip/hip_runtime.h>
#include <hip/hip_bf16.h>

// Problem constants (B=8192, D=128 from reference setup_inputs)
constexpr int Bh = 8192;
constexpr int Nn = 16384;   // 2*B
constexpr int Dd = 128;
constexpr float EPS = 1e-8f;
constexpr float LN2 = 0.69314718056f;

// Geometry (R10, best measured): 128-row x 64-col half-tiles, 16 KB staged B,
// 32 KB LDS dbuf. cum2(t) = t*(257-t); total 128*129 = 16512.
constexpr int K_TILES = 16;         // half-tiles per block
constexpr int N_TILES = 16512;
constexpr int N_BLOCKS = N_TILES / K_TILES;   // 1032, exact

typedef short bf16x8 __attribute__((ext_vector_type(8)));
typedef float f32x4 __attribute__((ext_vector_type(4)));

// ---- Kernel 1: fp32 -> bf16 z buffer (4 MB, per-XCD-L2-resident: R11 proved
// this buffer is load-bearing). Also zeroes rowsum, ticket counter, possum.
__global__ __launch_bounds__(256) void convert_kernel(const float4* __restrict__ za,
                                                      const float4* __restrict__ zb,
                                                      ushort* __restrict__ z,
                                                      float* __restrict__ rowsum,
                                                      int* __restrict__ counter,
                                                      float* __restrict__ possum) {
    const int t = blockIdx.x * 256 + threadIdx.x;        // 0 .. 524287
    constexpr int Q = (Bh * Dd) / 4;                     // 262144 float4 per input
    const float SCL = 1.69864363f;                       // sqrt(2 * 1.4426950409)
    float4 v = (t < Q) ? za[t] : zb[t - Q];
    union { ushort4 u4; __hip_bfloat16 h[4]; } cv;
    cv.h[0] = __float2bfloat16(v.x * SCL);
    cv.h[1] = __float2bfloat16(v.y * SCL);
    cv.h[2] = __float2bfloat16(v.z * SCL);
    cv.h[3] = __float2bfloat16(v.w * SCL);
    ((ushort4*)z)[t] = cv.u4;
    if (t < Nn) rowsum[t] = 0.f;
    if (t == 0) { counter[0] = 0; possum[0] = 0.f; }
}

// half-tile index g -> row tile t: largest t with cum2(t) = t*(257-t) <= g
__device__ __forceinline__ int row_tile_of(int g) {
    int t = (int)((257.0f - sqrtf((float)(66049 - 4 * g))) * 0.5f);
    t = t < 0 ? 0 : (t > 127 ? 127 : t);
    while (t * (257 - t) > g) --t;
    while ((t + 1) * (256 - t) <= g) ++t;
    return t;
}

// row-credit flush: reduce rs over the 16 col-lanes, one atomic per row
__device__ __forceinline__ void flush_rs(float* __restrict__ rowsum, int rowW,
                                         float (&rs)[2][4], int q, int c) {
#pragma unroll
    for (int s = 0; s < 2; ++s)
#pragma unroll
        for (int r = 0; r < 4; ++r) {
            float v = rs[s][r];
            v += __shfl_xor(v, 1);
            v += __shfl_xor(v, 2);
            v += __shfl_xor(v, 4);
            v += __shfl_xor(v, 8);
            if (c == 0) atomicAdd(&rowsum[rowW + s * 16 + q * 4 + r], v);
            rs[s][r] = 0.f;
        }
}

// col-credit flush (deferred one half-tile): reduce over q, one atomic per col
__device__ __forceinline__ void colflush(float* __restrict__ rowsum,
                                         float (&csumP)[4], int C0P, int lane, int c) {
#pragma unroll
    for (int st = 0; st < 4; ++st) {
        float v = csumP[st];
        v += __shfl_xor(v, 16);
        v += __shfl_xor(v, 32);
        if (lane < 16) atomicAdd(&rowsum[C0P + st * 16 + c], v);
    }
}

// Stage one 64-col x 128-K bf16 B half-tile (16 KB) into LDS via
// global_load_lds width-16, XOR-swizzled via the GLOBAL source address (m173).
__device__ __forceinline__ void stage_tile(const ushort* __restrict__ z, ushort* lbuf,
                                           int C0, int wave, int lane) {
#pragma unroll
    for (int i = 0; i < 4; ++i) {
        const int chunk = wave * 4 + i;              // 16 chunks of 1 KB
        const int r = (chunk << 2) + (lane >> 4);    // col 0..63 of this half-tile
        const int bl = ((lane & 15) ^ (r & 15)) << 4;  // swizzled byte-in-row
        const char* gp = (const char*)z + (((size_t)(C0 + r)) << 8) + bl;
        ushort* lp = lbuf + (chunk << 9);            // wave-uniform LDS base
        __builtin_amdgcn_global_load_lds((const __attribute__((address_space(1))) void*)gp,
                                         (__attribute__((address_space(3))) void*)lp,
                                         16, 0, 0);
    }
}

// ---- Kernel 2: R14 main + ILP-batched last-block finalize.
// R14 post-mortem: main's absolute VALU/MFMA/FETCH time == R10's, but +20 us
// idle — the finalize tail was 64 SEQUENTIAL agent-scope atomic loads
// (each ~450-600cy at the coherent point, bypassing per-XCD L2) + dependent
// logs, executed by ONE block after all others finished -> pure critical-path
// serial latency. R15 batches the loads 8-wide: 8 independent loads in
// flight per batch (compiler emits loads back-to-back, waits with counted
// vmcnt) -> ~8 round-trips instead of 64, tail ~2-3 us.
// Fences remain unnecessary: all cross-block data (rowsum, possum) is
// written solely with device-coherent atomics; the pre-ticket __syncthreads
// drains vmcnt(0) so each block's atomics complete before its ticket.
__global__ __launch_bounds__(256) void main_kernel(const ushort* __restrict__ z,
                                                   float* __restrict__ rowsum,
                                                   int* __restrict__ counter,
                                                   float* __restrict__ possum,
                                                   float* __restrict__ out) {
    __shared__ ushort ldsb[2][8192];      // 2 x 16 KB B half-tile double buffer

    const int tid = threadIdx.x;
    const int wave = tid >> 6;
    const int lane = tid & 63;
    const int q = lane >> 4;        // quad: 0..3
    const int c = lane & 15;        // 0..15
    const int g0 = blockIdx.x * K_TILES;

    int tr = row_tile_of(g0);
    int ct = 2 * tr + (g0 - tr * (257 - tr));   // col half-tile 0..255

    // per-lane swizzled LDS fragment offsets: logical 16B-unit (q+4kt) in row c
    int O[4];
#pragma unroll
    for (int kt = 0; kt < 4; ++kt) O[kt] = (c << 8) + ((((q + 4 * kt) ^ c)) << 4);

    bf16x8 afrag[2][4];
    float rs[2][4];
#pragma unroll
    for (int s = 0; s < 2; ++s)
#pragma unroll
        for (int r = 0; r < 4; ++r) rs[s][r] = 0.f;

    const f32x4 Z4 = {0.f, 0.f, 0.f, 0.f};

    float pacc = 0.f;               // this lane's positive-pair log contributions
    float csumP[4];
    int C0P = 0;
    bool pendP = false;
    int cur_tr = -1, rowW = 0, cur = 0;

    stage_tile(z, &ldsb[0][0], ct << 6, wave, lane);
    __syncthreads();

    for (int j = 0; j < K_TILES; ++j) {
        const int C0 = ct << 6;                 // column base (64-wide)
        const bool diag = ((ct >> 1) == tr);    // inside the diagonal 128x128

        if (tr != cur_tr) {                 // row-panel change: flush + reload A
            if (cur_tr >= 0) flush_rs(rowsum, rowW, rs, q, c);
            cur_tr = tr;
            rowW = (tr << 7) + wave * 32;   // this wave's 32-row base
#pragma unroll
            for (int s = 0; s < 2; ++s) {
                const ushort* ap = z + (size_t)(rowW + s * 16 + c) * Dd;
#pragma unroll
                for (int kt = 0; kt < 4; ++kt)
                    afrag[s][kt] = *(const bf16x8*)(ap + kt * 32 + q * 8);
            }
        }

        // deferred col-credit flush from previous half-tile
        if (pendP) { colflush(rowsum, csumP, C0P, lane, c); pendP = false; }

        // next half-tile coords + prefetch-stage into the other buffer
        int trN = tr, ctN = ct + 1;
        if (ctN == 256) { trN = tr + 1; ctN = 2 * trN; }
        if (j + 1 < K_TILES) stage_tile(z, &ldsb[cur ^ 1][0], ctN << 6, wave, lane);

        const char* lb = (const char*)&ldsb[cur][0];
        float csum[4];
#pragma unroll
        for (int st = 0; st < 4; ++st) csum[st] = 0.f;

        // ---- acc-pipelined phase loop: 5 phases over 4 st's (R8 schedule).
        f32x4 acc[2][2];
#pragma unroll
        for (int st = 0; st < 5; ++st) {
            const int p = st & 1;
            if (st < 4) {
                bf16x8 bcur[4];
#pragma unroll
                for (int kt = 0; kt < 4; ++kt)
                    bcur[kt] = *(const bf16x8*)(lb + O[kt] + st * 4096);
#pragma unroll
                for (int s = 0; s < 2; ++s)
                    acc[p][s] = __builtin_amdgcn_mfma_f32_16x16x32_bf16(afrag[s][0], bcur[0], Z4, 0, 0, 0);
#pragma unroll
                for (int kt = 1; kt < 4; ++kt) {
#pragma unroll
                    for (int s = 0; s < 2; ++s)
                        acc[p][s] = __builtin_amdgcn_mfma_f32_16x16x32_bf16(afrag[s][kt], bcur[kt], acc[p][s], 0, 0, 0);
                }
            }
            if (st > 0) {
                const int stP = st - 1;         // phase being finished
                const int pp = p ^ 1;
                const int gc0 = C0 + stP * 16;
#pragma unroll
                for (int s = 0; s < 2; ++s) {
                    const int R = rowW + s * 16;
                    float sp[4];
#pragma unroll
                    for (int r = 0; r < 4; ++r) {
                        float u = acc[pp][s][r];
                        // softplus scaled by log2e: max(u,0) + log2(1 + 2^-|u|)
                        float e = __builtin_amdgcn_exp2f(-fabsf(u));
                        sp[r] = fmaxf(u, 0.f) + __builtin_amdgcn_logf(1.f + e);
                    }
                    if (diag && gc0 == R) {               // zero self-similarity
#pragma unroll
                        for (int r = 0; r < 4; ++r)
                            if (c == q * 4 + r) sp[r] = 0.f;
                    }
                    if (gc0 == (R ^ Bh)) {                // positive-pair subtile
                        // (wave-uniform branch, rare; R<Bh guaranteed since
                        // R>=Bh would be below-diagonal)
#pragma unroll
                        for (int r = 0; r < 4; ++r)
                            if (c == q * 4 + r)
                                pacc += __logf(fmaxf(LN2 * sp[r], EPS));
                    }
#pragma unroll
                    for (int r = 0; r < 4; ++r) rs[s][r] += sp[r];
                    if (!diag) csum[stP] += (sp[0] + sp[1]) + (sp[2] + sp[3]);
                }
            }
        }

        if (!diag) {    // defer the col-credit atomics past the barrier
#pragma unroll
            for (int st = 0; st < 4; ++st) csumP[st] = csum[st];
            C0P = C0;
            pendP = true;
        }

        __syncthreads();        // drains vmcnt(0): stage + atomics all a phase old
        cur ^= 1;
        tr = trN;
        ct = ctN;
    }

    if (pendP) colflush(rowsum, csumP, C0P, lane, c);
    if (cur_tr >= 0) flush_rs(rowsum, rowW, rs, q, c);

    // positive-pair contribution: wave-reduce pacc, one atomic per wave (x2:
    // each pair element appears twice in the full N-sum)
    {
        float v = pacc;
#pragma unroll
        for (int m = 1; m < 64; m <<= 1) v += __shfl_xor(v, m);
        if (lane == 0 && v != 0.f) atomicAdd(possum, v + v);
    }

    // ---- last-block finalize (no fences; ILP-batched loads) ----
    __syncthreads();                       // barrier drain: all my atomics done
    int* shi = (int*)&ldsb[0][0];          // LDS dead now: reuse
    if (tid == 0) shi[0] = atomicAdd(counter, 1);
    __syncthreads();
    if (shi[0] == N_BLOCKS - 1) {
        float acc = 0.f;                   // sum of log(denom_i)
        // 16384 / 256 threads = 64 elems/thread; 8 batches of 8 independent
        // loads so ~8 coherent-point round-trips instead of 64.
#pragma unroll
        for (int b = 0; b < 8; ++b) {
            float v[8];
#pragma unroll
            for (int k = 0; k < 8; ++k)
                v[k] = __hip_atomic_load(&rowsum[tid + (b * 8 + k) * 256],
                                         __ATOMIC_RELAXED, __HIP_MEMORY_SCOPE_AGENT);
#pragma unroll
            for (int k = 0; k < 8; ++k)
                acc += __logf(fmaxf(LN2 * v[k], EPS));
        }
#pragma unroll
        for (int m = 1; m < 64; m <<= 1) acc += __shfl_xor(acc, m);
        __syncthreads();                   // all have read shi[0]
        float* red = (float*)&ldsb[0][0];
        if (lane == 0) red[wave] = acc;
        __syncthreads();
        if (tid == 0) {
            float ps = __hip_atomic_load(possum, __ATOMIC_RELAXED, __HIP_MEMORY_SCOPE_AGENT);
            float sumden = red[0] + red[1] + red[2] + red[3];
            out[0] = (sumden - ps) / (float)Nn;   // = -(possum - sum(log denom))/N
        }
    }
}

extern "C" void kernel_launch(void* const* d_in, const int* in_sizes, int n_in,
                              void* d_out, int out_size, void* d_ws, size_t ws_size,
                              hipStream_t stream) {
    const float* za = (const float*)d_in[0];
    const float* zb = (const float*)d_in[1];

    // workspace layout: z bf16 (4 MB) | rowsum (16384 f) | counter | possum
    ushort* z = (ushort*)d_ws;
    float* rowsum = (float*)((char*)d_ws + (size_t)Nn * Dd * 2);
    int* counter = (int*)(rowsum + Nn);
    float* possum = (float*)(rowsum + Nn + 32);
    float* out = (float*)d_out;

    convert_kernel<<<2048, 256, 0, stream>>>((const float4*)za, (const float4*)zb, z, rowsum, counter, possum);
    main_kernel<<<N_BLOCKS, 256, 0, stream>>>(z, rowsum, counter, possum, out);
}